// Round 10
// baseline (1290.554 us; speedup 1.0000x reference)
//
#include <hip/hip_runtime.h>

#define N_USERS_C 100000
#define N_OUTFITS_C 100000
#define N_NODES_C 200000
#define EMBED_C 128
#define LAYERS_C 3
#define NEG_SLOPE_C 0.01f
#define EPS_C 1e-12f

#define NCOARSE 25
#define CSHIFT 13          // 8192 rows per coarse bucket
#define CBCAP 270336       // mean 262144 + 16 sigma
#define NFINE 1600         // 64 fine per coarse, 128 rows each
#define FB_ROWS 128
#define FCAP 4736          // mean 4096 + 10 sigma
#define NFB_USED 1563      // ceil(200000/128)

typedef float f32x4 __attribute__((ext_vector_type(4)));
typedef float f32x2 __attribute__((ext_vector_type(2)));
typedef int i32x2 __attribute__((ext_vector_type(2)));
typedef short s16x8 __attribute__((ext_vector_type(8)));
typedef __bf16 bf16x8 __attribute__((ext_vector_type(8)));

// ---- MFMA shim: works whether the builtin wants short8 or bf16x8 ----
template <typename T>
__device__ inline auto mfma_bf16_(T a, T b, f32x4 c, int)
    -> decltype(__builtin_amdgcn_mfma_f32_16x16x32_bf16(a, b, c, 0, 0, 0)) {
  return __builtin_amdgcn_mfma_f32_16x16x32_bf16(a, b, c, 0, 0, 0);
}
template <typename T>
__device__ inline f32x4 mfma_bf16_(T a, T b, f32x4 c, long) {
  union U { T s; bf16x8 b; };
  U ua; ua.s = a;
  U ub; ub.s = b;
  return __builtin_amdgcn_mfma_f32_16x16x32_bf16(ua.b, ub.b, c, 0, 0, 0);
}
__device__ inline f32x4 MFMA16(s16x8 a, s16x8 b, f32x4 c) {
  return mfma_bf16_(a, b, c, 0);
}

// ---- bf16 helpers (manual RNE) ----
__device__ inline unsigned short f2bf(float x) {
  unsigned u = __builtin_bit_cast(unsigned, x);
  u = (u + 0x7fffu + ((u >> 16) & 1u)) >> 16;
  return (unsigned short)u;
}
__device__ inline float bf2f(unsigned short h) {
  unsigned u = ((unsigned)h) << 16;
  return __builtin_bit_cast(float, u);
}
__device__ inline float bflo(unsigned u) {
  return __builtin_bit_cast(float, u << 16);
}
__device__ inline float bfhi(unsigned u) {
  return __builtin_bit_cast(float, u & 0xffff0000u);
}

// ---- nontemporal vector helpers (ext_vector types only) ----
__device__ inline f32x4 nt_load_f4(const float* p) {
  return __builtin_nontemporal_load((const f32x4*)p);
}
__device__ inline void nt_store_f4(float* p, f32x4 v) {
  __builtin_nontemporal_store(v, (f32x4*)p);
}
__device__ inline i32x2 nt_load_i2(const int2* p) {
  return __builtin_nontemporal_load((const i32x2*)p);
}
__device__ inline void nt_store_i2(int2* p, int x, int y) {
  i32x2 v;
  v.x = x;
  v.y = y;
  __builtin_nontemporal_store(v, (i32x2*)p);
}

// ---------------------------------------------------------------- init cursors
__global__ __launch_bounds__(256) void init_gcur(int* __restrict__ cg,
                                                 int* __restrict__ fg) {
  int t = blockIdx.x * 256 + threadIdx.x;
  if (t < NCOARSE) cg[t] = t * CBCAP;
  if (t < NFINE) fg[t] = t * FCAP;
}

// ---------------------------------------------------------------- init ego/out
__global__ __launch_bounds__(256) void init_ego_out(
    const float* __restrict__ user_emb, const int* __restrict__ u_id,
    const float* __restrict__ o_emb, unsigned short* __restrict__ ego,
    float* __restrict__ out) {
  int i4 = blockIdx.x * blockDim.x + threadIdx.x;
  if (i4 >= N_NODES_C * (EMBED_C / 4)) return;
  int r = i4 >> 5;
  int c4 = i4 & 31;
  f32x4 v;
  if (r < N_USERS_C) {
    int src = u_id[r];
    v = nt_load_f4(user_emb + ((size_t)src * 32 + c4) * 4);
  } else {
    v = nt_load_f4(o_emb + ((size_t)(r - N_USERS_C) * 32 + c4) * 4);
  }
  nt_store_f4(out + (size_t)i4 * 4, v);
  ushort4 h;
  unsigned short* hp = (unsigned short*)&h;
#pragma unroll
  for (int j = 0; j < 4; ++j) hp[j] = f2bf(v[j]);
  reinterpret_cast<ushort4*>(ego)[i4] = h;
}

// ---------------------------------------------------------------- A1: coarse partition
__global__ __launch_bounds__(256) void partition_edges(
    const int* __restrict__ erow, const int* __restrict__ ecol,
    const float* __restrict__ eval, int* __restrict__ cgcur,
    int2* __restrict__ cstage, int nnz) {
  __shared__ int2 scratch[2048];
  __shared__ unsigned char sbid[2048];
  __shared__ int hist[NCOARSE], lbase[NCOARSE], gbase[NCOARSE];
  int t = threadIdx.x;
  int base = blockIdx.x * 2048;
  if (base + 2048 > nnz) return;  // nnz divisible by 2048
  if (t < NCOARSE) hist[t] = 0;
  __syncthreads();
  int rowv[8], colv[8], bb[8], rk[8], vv[8];
#pragma unroll
  for (int r = 0; r < 8; ++r) {
    int e = base + t + r * 256;
    rowv[r] = __builtin_nontemporal_load(&erow[e]);
    colv[r] = __builtin_nontemporal_load(&ecol[e]);
    float fv = __builtin_nontemporal_load(&eval[e]);
    vv[r] = __builtin_bit_cast(int, fv);
  }
#pragma unroll
  for (int r = 0; r < 8; ++r) {
    bb[r] = rowv[r] >> CSHIFT;
    rk[r] = atomicAdd(&hist[bb[r]], 1);
  }
  __syncthreads();
  if (t < 64) {
    int v = (t < NCOARSE) ? hist[t] : 0;
    int s = v;
#pragma unroll
    for (int off = 1; off < 32; off <<= 1) {
      int n = __shfl_up(s, off);
      if (t >= off) s += n;
    }
    if (t < NCOARSE) lbase[t] = s - v;
  }
  __syncthreads();
  if (t < NCOARSE) gbase[t] = atomicAdd(&cgcur[t], hist[t]);
  __syncthreads();
#pragma unroll
  for (int r = 0; r < 8; ++r) {
    int slot = lbase[bb[r]] + rk[r];
    int2 p;
    p.x = (int)(((unsigned)(rowv[r] & ((1 << CSHIFT) - 1)) << 18) |
                (unsigned)colv[r]);
    p.y = vv[r];
    scratch[slot] = p;
    sbid[slot] = (unsigned char)bb[r];
  }
  __syncthreads();
#pragma unroll
  for (int q = 0; q < 8; ++q) {
    int i = t + q * 256;
    int b = sbid[i];
    int2 s2 = scratch[i];
    nt_store_i2(&cstage[(size_t)gbase[b] + (i - lbase[b])], s2.x, s2.y);
  }
}

// ---------------------------------------------------------------- A2: refine 25 -> 1600
__global__ __launch_bounds__(256) void refine_buckets(
    const int2* __restrict__ cstage, const int* __restrict__ cgcur,
    int* __restrict__ fgcur, int2* __restrict__ fstage) {
  __shared__ int2 scratch[2048];
  __shared__ short sbid[2048];
  __shared__ int hist[64], lbase[64], gbase[64];
  int b = blockIdx.x >> 5;  // coarse bucket
  int j = blockIdx.x & 31;  // chunk
  int t = threadIdx.x;
  int cnt = cgcur[b] - b * CBCAP;
  int s0 = (int)(((long)cnt * j) >> 5);
  int s1 = (int)(((long)cnt * (j + 1)) >> 5);
  const int2* src = cstage + (size_t)b * CBCAP;
  int fb0 = b * 64;
  for (int t0 = s0; t0 < s1; t0 += 2048) {
    int tn = s1 - t0;
    if (tn > 2048) tn = 2048;
    if (t < 64) hist[t] = 0;
    __syncthreads();
    i32x2 p[8];
    int sub[8], rk[8];
#pragma unroll
    for (int r = 0; r < 8; ++r) {
      int i = t + r * 256;
      if (i < tn) {
        p[r] = nt_load_i2(&src[t0 + i]);
        sub[r] = (int)(((unsigned)p[r].x >> 25) & 63);
        rk[r] = atomicAdd(&hist[sub[r]], 1);
      }
    }
    __syncthreads();
    if (t < 64) {
      int v = hist[t];
      int s = v;
#pragma unroll
      for (int off = 1; off < 64; off <<= 1) {
        int n = __shfl_up(s, off);
        if (t >= off) s += n;
      }
      lbase[t] = s - v;
    }
    __syncthreads();
    if (t < 64) gbase[t] = atomicAdd(&fgcur[fb0 + t], hist[t]);
    __syncthreads();
#pragma unroll
    for (int r = 0; r < 8; ++r) {
      int i = t + r * 256;
      if (i < tn) {
        int slot = lbase[sub[r]] + rk[r];
        int2 q;
        q.x = p[r].x & 0x1FFFFFF;  // col(18) + rowlocal7 (bits 18..24)
        q.y = p[r].y;
        scratch[slot] = q;
        sbid[slot] = (short)sub[r];
      }
    }
    __syncthreads();
    for (int i = t; i < tn; i += 256) {
      int bs = sbid[i];
      int2 s2 = scratch[i];
      nt_store_i2(&fstage[(size_t)gbase[bs] + (i - lbase[bs])], s2.x, s2.y);
    }
    __syncthreads();
  }
}

// ---------------------------------------------------------------- sort buckets ONCE
// Reg-stage bucket edges, counting-sort by rowlocal in LDS, emit row-sorted
// (col,val) list + per-row (start,count). Runs once; spmm consumes 3x.
__global__ __launch_bounds__(512) void sort_bucket(
    const int2* __restrict__ fstage, const int* __restrict__ fgcur,
    int2* __restrict__ esorted, int* __restrict__ gs, int* __restrict__ gn) {
  __shared__ int2 se[FCAP];
  __shared__ int sbase[128];
  __shared__ int scur[128];
  __shared__ int shist[128];
  int t = threadIdx.x;
  int fb = blockIdx.x;
  int cnt = fgcur[fb] - fb * FCAP;
  if (t < 128) shist[t] = 0;
  __syncthreads();
  const int2* src = fstage + (size_t)fb * FCAP;
  i32x2 pr[10];  // ceil(FCAP/512) = 10, statically indexed
#pragma unroll
  for (int q = 0; q < 10; ++q) {
    int i = t + q * 512;
    if (i < cnt) {
      pr[q] = nt_load_i2(&src[i]);
      atomicAdd(&shist[((unsigned)pr[q].x >> 18) & 127], 1);
    }
  }
  __syncthreads();
  if (t < 64) {
    int h0 = shist[2 * t], h1 = shist[2 * t + 1];
    int s = h0 + h1;
    int pref = s;
#pragma unroll
    for (int off = 1; off < 64; off <<= 1) {
      int n = __shfl_up(pref, off);
      if (t >= off) pref += n;
    }
    int ex = pref - s;
    sbase[2 * t] = ex;
    scur[2 * t] = ex;
    sbase[2 * t + 1] = ex + h0;
    scur[2 * t + 1] = ex + h0;
  }
  __syncthreads();
#pragma unroll
  for (int q = 0; q < 10; ++q) {
    int i = t + q * 512;
    if (i < cnt) {
      int rw = (int)(((unsigned)pr[q].x >> 18) & 127);
      int pos = atomicAdd(&scur[rw], 1);
      int2 o;
      o.x = pr[q].x & 0x3FFFF;
      o.y = pr[q].y;
      se[pos] = o;
    }
  }
  __syncthreads();
  for (int i = t; i < cnt; i += 512)
    esorted[(size_t)fb * FCAP + i] = se[i];
  if (t < 128) {
    gs[fb * 128 + t] = fb * FCAP + sbase[t];
    gn[fb * 128 + t] = scur[t] - sbase[t];
  }
}

// ---------------------------------------------------------------- W prep
__global__ __launch_bounds__(256) void prep_w(
    const float* __restrict__ fc1_w, const float* __restrict__ fc2_w,
    unsigned short* __restrict__ whi, unsigned short* __restrict__ wlo) {
  int idx = blockIdx.x * 256 + threadIdx.x;
  if (idx >= LAYERS_C * 128 * 256) return;
  int k = idx & 255;
  int j = (idx >> 8) & 127;
  int l = idx >> 15;
  float v = (k < 128) ? fc1_w[((size_t)l * 128 + j) * 128 + k]
                      : fc2_w[((size_t)l * 128 + j) * 128 + (k - 128)];
  unsigned short h = f2bf(v);
  whi[idx] = h;
  wlo[idx] = f2bf(v - bf2f(h));
}

// ---------------------------------------------------------------- SpMM (pre-sorted, no LDS)
// Wave owns a row; edges streamed via uniform loads; 8-deep gather unroll.
__global__ __launch_bounds__(512) void spmm_sorted(
    const int2* __restrict__ esorted, const int* __restrict__ gs,
    const int* __restrict__ gn, const unsigned* __restrict__ ego,
    unsigned* __restrict__ side_bf) {
  int t = threadIdx.x;
  int wave = t >> 6, lane = t & 63;
  int fb = blockIdx.x;
  for (int r = wave; r < FB_ROWS; r += 8) {
    int grow = fb * FB_ROWS + r;
    if (grow >= N_NODES_C) break;
    int s = gs[fb * 128 + r];
    int n = gn[fb * 128 + r];
    const int2* ep = esorted + s;
    float ax = 0.f, ay = 0.f;
    int tt = 0;
    for (; tt + 8 <= n; tt += 8) {
      unsigned u[8];
      float vt[8];
#pragma unroll
      for (int q = 0; q < 8; ++q) {
        int2 p = ep[tt + q];  // lane-uniform -> one line per edge
        vt[q] = __builtin_bit_cast(float, p.y);
        u[q] = ego[(size_t)p.x * 64 + lane];
      }
#pragma unroll
      for (int q = 0; q < 8; ++q) {
        ax = fmaf(vt[q], bflo(u[q]), ax);
        ay = fmaf(vt[q], bfhi(u[q]), ay);
      }
    }
    for (; tt < n; ++tt) {
      int2 p = ep[tt];
      float vv = __builtin_bit_cast(float, p.y);
      unsigned uu = ego[(size_t)p.x * 64 + lane];
      ax = fmaf(vv, bflo(uu), ax);
      ay = fmaf(vv, bfhi(uu), ay);
    }
    unsigned pk = (unsigned)f2bf(ax) | ((unsigned)f2bf(ay) << 16);
    side_bf[(size_t)grow * 64 + lane] = pk;
  }
}

// ---------------------------------------------------------------- fused dense layer (MFMA, split-bf16)
// Y[32][128] = Z[32][256] @ Wcat^T, Z = [side_bf16 | ego*side], ego bf16.
// side half: 2-term MFMA; prod half: 3-term.
__global__ __launch_bounds__(256) void dense_mfma(
    const unsigned short* __restrict__ side_bf, unsigned short* __restrict__ ego,
    const unsigned short* __restrict__ whi, const unsigned short* __restrict__ wlo,
    const float* __restrict__ b1, const float* __restrict__ b2,
    float* __restrict__ out) {
  __shared__ unsigned short A_hi[32 * 256];
  __shared__ unsigned short A_lo[32 * 256];  // only prod half (k>=128) used
  int t = threadIdx.x;
  int lane = t & 63;
  int w = t >> 6;
  int l15 = lane & 15;
  int lg = lane >> 4;
  int nb = blockIdx.x * 32;

#pragma unroll
  for (int i = 0; i < 4; ++i) {
    int f = i * 256 + t;
    int row = f >> 5;
    int c4 = f & 31;
    size_t g = (size_t)(nb + row) * 32 + c4;
    ushort4 sv = reinterpret_cast<const ushort4*>(side_bf)[g];
    ushort4 hv = reinterpret_cast<const ushort4*>(ego)[g];
    const unsigned short* svp = (const unsigned short*)&sv;
    const unsigned short* hvp = (const unsigned short*)&hv;
    ushort4 ph, pl;
    unsigned short* php = (unsigned short*)&ph;
    unsigned short* plp = (unsigned short*)&pl;
#pragma unroll
    for (int j = 0; j < 4; ++j) {
      float p = bf2f(svp[j]) * bf2f(hvp[j]);
      unsigned short hp2 = f2bf(p);
      php[j] = hp2;
      plp[j] = f2bf(p - bf2f(hp2));
    }
    int swz = (row & 7) << 4;
    int base_s = (row * 512 + c4 * 8) ^ swz;
    int base_p = (row * 512 + 256 + c4 * 8) ^ swz;
    *(ushort4*)((char*)A_hi + base_s) = sv;   // side bf16 (no residual)
    *(ushort4*)((char*)A_hi + base_p) = ph;
    *(ushort4*)((char*)A_lo + base_p) = pl;
  }

  float bias[2];
#pragma unroll
  for (int ntl = 0; ntl < 2; ++ntl) {
    int col = (w * 2 + ntl) * 16 + l15;
    bias[ntl] = b1[col] + b2[col];
  }

  __syncthreads();

  f32x4 zero = {0.f, 0.f, 0.f, 0.f};
  f32x4 acc[2][2] = {{zero, zero}, {zero, zero}};
#pragma unroll
  for (int kt = 0; kt < 8; ++kt) {
    int kb = kt * 64 + lg * 16;
    s16x8 a_hi[2], a_lo[2];
#pragma unroll
    for (int mt = 0; mt < 2; ++mt) {
      int row = mt * 16 + l15;
      int off = (row * 512 + kb) ^ ((row & 7) << 4);
      a_hi[mt] = *(const s16x8*)((const char*)A_hi + off);
      if (kt >= 4) a_lo[mt] = *(const s16x8*)((const char*)A_lo + off);
    }
    s16x8 b_hi[2], b_lo[2];
#pragma unroll
    for (int ntl = 0; ntl < 2; ++ntl) {
      int j = (w * 2 + ntl) * 16 + l15;
      size_t woff = (size_t)j * 256 + kt * 32 + lg * 8;
      b_hi[ntl] = *(const s16x8*)(whi + woff);
      b_lo[ntl] = *(const s16x8*)(wlo + woff);
    }
#pragma unroll
    for (int mt = 0; mt < 2; ++mt)
#pragma unroll
      for (int ntl = 0; ntl < 2; ++ntl) {
        acc[mt][ntl] = MFMA16(a_hi[mt], b_hi[ntl], acc[mt][ntl]);
        acc[mt][ntl] = MFMA16(a_hi[mt], b_lo[ntl], acc[mt][ntl]);
        if (kt >= 4)
          acc[mt][ntl] = MFMA16(a_lo[mt], b_hi[ntl], acc[mt][ntl]);
      }
  }

  __syncthreads();  // done reading A; reuse as y tile

  float* ylds = (float*)A_hi;
#pragma unroll
  for (int mt = 0; mt < 2; ++mt)
#pragma unroll
    for (int ntl = 0; ntl < 2; ++ntl) {
      int col = (w * 2 + ntl) * 16 + l15;
#pragma unroll
      for (int r = 0; r < 4; ++r) {
        int row = mt * 16 + lg * 4 + r;
        float a = acc[mt][ntl][r] + bias[ntl];
        float yv = (a >= 0.f) ? a : NEG_SLOPE_C * a;
        int off = (row * 512 + col * 4) ^ ((row & 7) << 4);
        *(float*)((char*)ylds + off) = yv;
      }
    }
  __syncthreads();

#pragma unroll
  for (int i = 0; i < 4; ++i) {
    int f = i * 256 + t;
    int row = f >> 5;
    int c4 = f & 31;
    int off = (row * 512 + c4 * 16) ^ ((row & 7) << 4);
    f32x4 y = *(f32x4*)((char*)ylds + off);
    float ss = y.x * y.x + y.y * y.y + y.z * y.z + y.w * y.w;
#pragma unroll
    for (int m = 1; m <= 16; m <<= 1) ss += __shfl_xor(ss, m);
    float scale = 1.0f / fmaxf(sqrtf(ss), EPS_C);
    size_t g = (size_t)(nb + row) * 32 + c4;
    ushort4 h;
    unsigned short* hp = (unsigned short*)&h;
#pragma unroll
    for (int jj = 0; jj < 4; ++jj) hp[jj] = f2bf(y[jj]);
    reinterpret_cast<ushort4*>(ego)[g] = h;
    f32x4 o = *(const f32x4*)(out + g * 4);
    o.x += y.x * scale;
    o.y += y.y * scale;
    o.z += y.z * scale;
    o.w += y.w * scale;
    *(f32x4*)(out + g * 4) = o;
  }
}

// ---------------------------------------------------------------- launch
extern "C" void kernel_launch(void* const* d_in, const int* in_sizes, int n_in,
                              void* d_out, int out_size, void* d_ws,
                              size_t ws_size, hipStream_t stream) {
  const int* erow = (const int*)d_in[0];
  const int* ecol = (const int*)d_in[1];
  const float* eval = (const float*)d_in[2];
  const float* o_emb = (const float*)d_in[3];
  const int* u_id = (const int*)d_in[4];
  const float* user_emb = (const float*)d_in[5];
  const float* fc1_w = (const float*)d_in[6];
  const float* fc1_b = (const float*)d_in[7];
  const float* fc2_w = (const float*)d_in[8];
  const float* fc2_b = (const float*)d_in[9];
  float* out = (float*)d_out;
  int nnz = in_sizes[0];

  char* ws = (char*)d_ws;
  size_t off = 0;
  auto alloc = [&](size_t bytes) {
    void* p = ws + off;
    off += (bytes + 255) & ~(size_t)255;
    return p;
  };
  unsigned short* ego = (unsigned short*)alloc((size_t)N_NODES_C * EMBED_C * 2);
  // union region: cstage (54.1 MB, dead after refine) / side_bf (51.2 MB)
  char* unionAB = (char*)alloc((size_t)NCOARSE * CBCAP * 8);
  int2* cstage = (int2*)unionAB;
  unsigned* side_bf = (unsigned*)unionAB;
  int2* fstage = (int2*)alloc((size_t)NFINE * FCAP * 8);
  int2* esorted = (int2*)alloc((size_t)NFB_USED * FCAP * 8);
  int* gs = (int*)alloc((size_t)NFB_USED * 128 * 4);
  int* gn = (int*)alloc((size_t)NFB_USED * 128 * 4);
  int* cgcur = (int*)alloc(NCOARSE * 4);
  int* fgcur = (int*)alloc(NFINE * 4);
  unsigned short* whi = (unsigned short*)alloc((size_t)LAYERS_C * 128 * 256 * 2);
  unsigned short* wlo = (unsigned short*)alloc((size_t)LAYERS_C * 128 * 256 * 2);

  init_gcur<<<(NFINE + 255) / 256, 256, 0, stream>>>(cgcur, fgcur);
  init_ego_out<<<(N_NODES_C * 32 + 255) / 256, 256, 0, stream>>>(
      user_emb, u_id, o_emb, ego, out);
  partition_edges<<<nnz / 2048, 256, 0, stream>>>(erow, ecol, eval, cgcur,
                                                  cstage, nnz);
  refine_buckets<<<NCOARSE * 32, 256, 0, stream>>>(cstage, cgcur, fgcur,
                                                   fstage);
  sort_bucket<<<NFB_USED, 512, 0, stream>>>(fstage, fgcur, esorted, gs, gn);
  prep_w<<<(LAYERS_C * 128 * 256 + 255) / 256, 256, 0, stream>>>(fc1_w, fc2_w,
                                                                 whi, wlo);
  for (int l = 0; l < LAYERS_C; ++l) {
    spmm_sorted<<<NFB_USED, 512, 0, stream>>>(esorted, gs, gn,
                                              (const unsigned*)ego, side_bf);
    dense_mfma<<<N_NODES_C / 32, 256, 0, stream>>>(
        (const unsigned short*)side_bf, ego, whi + (size_t)l * 32768,
        wlo + (size_t)l * 32768, fc1_b + l * EMBED_C, fc2_b + l * EMBED_C, out);
  }
}

// Round 11
// 1158.606 us; speedup vs baseline: 1.1139x; 1.1139x over previous
//
#include <hip/hip_runtime.h>

#define N_USERS_C 100000
#define N_OUTFITS_C 100000
#define N_NODES_C 200000
#define EMBED_C 128
#define LAYERS_C 3
#define NEG_SLOPE_C 0.01f
#define EPS_C 1e-12f

#define NCOARSE 25
#define CSHIFT 13          // 8192 rows per coarse bucket
#define CBCAP 270336       // mean 262144 + 16 sigma
#define NFINE 1600         // 64 fine per coarse, 128 rows each
#define FB_ROWS 128
#define FCAP 4736          // mean 4096 + 10 sigma
#define NFB_USED 1563      // ceil(200000/128)

typedef float f32x4 __attribute__((ext_vector_type(4)));
typedef float f32x2 __attribute__((ext_vector_type(2)));
typedef int i32x2 __attribute__((ext_vector_type(2)));
typedef short s16x8 __attribute__((ext_vector_type(8)));
typedef __bf16 bf16x8 __attribute__((ext_vector_type(8)));

// ---- MFMA shim: works whether the builtin wants short8 or bf16x8 ----
template <typename T>
__device__ inline auto mfma_bf16_(T a, T b, f32x4 c, int)
    -> decltype(__builtin_amdgcn_mfma_f32_16x16x32_bf16(a, b, c, 0, 0, 0)) {
  return __builtin_amdgcn_mfma_f32_16x16x32_bf16(a, b, c, 0, 0, 0);
}
template <typename T>
__device__ inline f32x4 mfma_bf16_(T a, T b, f32x4 c, long) {
  union U { T s; bf16x8 b; };
  U ua; ua.s = a;
  U ub; ub.s = b;
  return __builtin_amdgcn_mfma_f32_16x16x32_bf16(ua.b, ub.b, c, 0, 0, 0);
}
__device__ inline f32x4 MFMA16(s16x8 a, s16x8 b, f32x4 c) {
  return mfma_bf16_(a, b, c, 0);
}

// ---- bf16 helpers (manual RNE) ----
__device__ inline unsigned short f2bf(float x) {
  unsigned u = __builtin_bit_cast(unsigned, x);
  u = (u + 0x7fffu + ((u >> 16) & 1u)) >> 16;
  return (unsigned short)u;
}
__device__ inline float bf2f(unsigned short h) {
  unsigned u = ((unsigned)h) << 16;
  return __builtin_bit_cast(float, u);
}
__device__ inline float bflo(unsigned u) {
  return __builtin_bit_cast(float, u << 16);
}
__device__ inline float bfhi(unsigned u) {
  return __builtin_bit_cast(float, u & 0xffff0000u);
}

// ---- nontemporal helpers (inputs only) ----
__device__ inline f32x4 nt_load_f4(const float* p) {
  return __builtin_nontemporal_load((const f32x4*)p);
}

// ---------------------------------------------------------------- init cursors
__global__ __launch_bounds__(256) void init_gcur(int* __restrict__ cg,
                                                 int* __restrict__ fg) {
  int t = blockIdx.x * 256 + threadIdx.x;
  if (t < NCOARSE) cg[t] = t * CBCAP;
  if (t < NFINE) fg[t] = t * FCAP;
}

// ---------------------------------------------------------------- init ego/out
__global__ __launch_bounds__(256) void init_ego_out(
    const float* __restrict__ user_emb, const int* __restrict__ u_id,
    const float* __restrict__ o_emb, unsigned short* __restrict__ ego,
    float* __restrict__ out) {
  int i4 = blockIdx.x * blockDim.x + threadIdx.x;
  if (i4 >= N_NODES_C * (EMBED_C / 4)) return;
  int r = i4 >> 5;
  int c4 = i4 & 31;
  f32x4 v;
  if (r < N_USERS_C) {
    int src = u_id[r];
    v = nt_load_f4(user_emb + ((size_t)src * 32 + c4) * 4);
  } else {
    v = nt_load_f4(o_emb + ((size_t)(r - N_USERS_C) * 32 + c4) * 4);
  }
  *(f32x4*)(out + (size_t)i4 * 4) = v;
  ushort4 h;
  unsigned short* hp = (unsigned short*)&h;
#pragma unroll
  for (int j = 0; j < 4; ++j) hp[j] = f2bf(v[j]);
  reinterpret_cast<ushort4*>(ego)[i4] = h;
}

// ---------------------------------------------------------------- A1: coarse partition
__global__ __launch_bounds__(256) void partition_edges(
    const int* __restrict__ erow, const int* __restrict__ ecol,
    const float* __restrict__ eval, int* __restrict__ cgcur,
    int2* __restrict__ cstage, int nnz) {
  __shared__ int2 scratch[2048];
  __shared__ unsigned char sbid[2048];
  __shared__ int hist[NCOARSE], lbase[NCOARSE], gbase[NCOARSE];
  int t = threadIdx.x;
  int base = blockIdx.x * 2048;
  if (base + 2048 > nnz) return;  // nnz divisible by 2048
  if (t < NCOARSE) hist[t] = 0;
  __syncthreads();
  int rowv[8], colv[8], bb[8], rk[8], vv[8];
#pragma unroll
  for (int r = 0; r < 8; ++r) {
    int e = base + t + r * 256;
    rowv[r] = __builtin_nontemporal_load(&erow[e]);
    colv[r] = __builtin_nontemporal_load(&ecol[e]);
    float fv = __builtin_nontemporal_load(&eval[e]);
    vv[r] = __builtin_bit_cast(int, fv);
  }
#pragma unroll
  for (int r = 0; r < 8; ++r) {
    bb[r] = rowv[r] >> CSHIFT;
    rk[r] = atomicAdd(&hist[bb[r]], 1);
  }
  __syncthreads();
  if (t < 64) {
    int v = (t < NCOARSE) ? hist[t] : 0;
    int s = v;
#pragma unroll
    for (int off = 1; off < 32; off <<= 1) {
      int n = __shfl_up(s, off);
      if (t >= off) s += n;
    }
    if (t < NCOARSE) lbase[t] = s - v;
  }
  __syncthreads();
  if (t < NCOARSE) gbase[t] = atomicAdd(&cgcur[t], hist[t]);
  __syncthreads();
#pragma unroll
  for (int r = 0; r < 8; ++r) {
    int slot = lbase[bb[r]] + rk[r];
    int2 p;
    p.x = (int)(((unsigned)(rowv[r] & ((1 << CSHIFT) - 1)) << 18) |
                (unsigned)colv[r]);
    p.y = vv[r];
    scratch[slot] = p;
    sbid[slot] = (unsigned char)bb[r];
  }
  __syncthreads();
#pragma unroll
  for (int q = 0; q < 8; ++q) {
    int i = t + q * 256;
    int b = sbid[i];
    cstage[(size_t)gbase[b] + (i - lbase[b])] = scratch[i];
  }
}

// ---------------------------------------------------------------- A2: refine 25 -> 1600 (4096-edge tiles)
__global__ __launch_bounds__(256) void refine_buckets(
    const int2* __restrict__ cstage, const int* __restrict__ cgcur,
    int* __restrict__ fgcur, int2* __restrict__ fstage) {
  __shared__ int2 scratch[4096];   // 32 KB
  __shared__ short sbid[4096];     // 8 KB
  __shared__ int hist[64], lbase[64], gbase[64];
  int b = blockIdx.x >> 5;  // coarse bucket
  int j = blockIdx.x & 31;  // chunk
  int t = threadIdx.x;
  int cnt = cgcur[b] - b * CBCAP;
  int s0 = (int)(((long)cnt * j) >> 5);
  int s1 = (int)(((long)cnt * (j + 1)) >> 5);
  const int2* src = cstage + (size_t)b * CBCAP;
  int fb0 = b * 64;
  for (int t0 = s0; t0 < s1; t0 += 4096) {
    int tn = s1 - t0;
    if (tn > 4096) tn = 4096;
    if (t < 64) hist[t] = 0;
    __syncthreads();
    i32x2 p[16];
    int sub[16], rk[16];
#pragma unroll
    for (int r = 0; r < 16; ++r) {
      int i = t + r * 256;
      if (i < tn) {
        p[r] = *(const i32x2*)&src[t0 + i];
        sub[r] = (int)(((unsigned)p[r].x >> 25) & 63);
        rk[r] = atomicAdd(&hist[sub[r]], 1);
      }
    }
    __syncthreads();
    if (t < 64) {
      int v = hist[t];
      int s = v;
#pragma unroll
      for (int off = 1; off < 64; off <<= 1) {
        int n = __shfl_up(s, off);
        if (t >= off) s += n;
      }
      lbase[t] = s - v;
    }
    __syncthreads();
    if (t < 64) gbase[t] = atomicAdd(&fgcur[fb0 + t], hist[t]);
    __syncthreads();
#pragma unroll
    for (int r = 0; r < 16; ++r) {
      int i = t + r * 256;
      if (i < tn) {
        int slot = lbase[sub[r]] + rk[r];
        int2 q;
        q.x = p[r].x & 0x1FFFFFF;  // col(18) + rowlocal7 (bits 18..24)
        q.y = p[r].y;
        scratch[slot] = q;
        sbid[slot] = (short)sub[r];
      }
    }
    __syncthreads();
    for (int i = t; i < tn; i += 256) {
      int bs = sbid[i];
      fstage[(size_t)gbase[bs] + (i - lbase[bs])] = scratch[i];
    }
    __syncthreads();
  }
}

// ---------------------------------------------------------------- W prep
__global__ __launch_bounds__(256) void prep_w(
    const float* __restrict__ fc1_w, const float* __restrict__ fc2_w,
    unsigned short* __restrict__ whi, unsigned short* __restrict__ wlo) {
  int idx = blockIdx.x * 256 + threadIdx.x;
  if (idx >= LAYERS_C * 128 * 256) return;
  int k = idx & 255;
  int j = (idx >> 8) & 127;
  int l = idx >> 15;
  float v = (k < 128) ? fc1_w[((size_t)l * 128 + j) * 128 + k]
                      : fc2_w[((size_t)l * 128 + j) * 128 + (k - 128)];
  unsigned short h = f2bf(v);
  whi[idx] = h;
  wlo[idx] = f2bf(v - bf2f(h));
}

// ---------------------------------------------------------------- SpMM per fine bucket
// Single fstage read (reg-staged), LDS counting sort, per-row register
// accumulation (wave owns a whole 128-col row; metadata via uniform LDS reads).
__global__ __launch_bounds__(512, 4) void spmm_bucket(
    const int2* __restrict__ fstage, const int* __restrict__ fgcur,
    const unsigned* __restrict__ ego, unsigned* __restrict__ side_bf) {
  __shared__ int2 se[FCAP];     // 37888 B sorted edges
  __shared__ int sbase[128];
  __shared__ int scur[128];
  __shared__ int shist[128];
  int t = threadIdx.x;
  int fb = blockIdx.x;
  int cnt = fgcur[fb] - fb * FCAP;
  if (t < 128) shist[t] = 0;
  __syncthreads();
  const int2* src = fstage + (size_t)fb * FCAP;
  // single pass: reg-stage + histogram
  i32x2 pr[10];  // ceil(FCAP/512) = 10, statically indexed
#pragma unroll
  for (int q = 0; q < 10; ++q) {
    int i = t + q * 512;
    if (i < cnt) {
      pr[q] = *(const i32x2*)&src[i];
      atomicAdd(&shist[((unsigned)pr[q].x >> 18) & 127], 1);
    }
  }
  __syncthreads();
  // scan (wave 0, 2 elems/lane)
  if (t < 64) {
    int h0 = shist[2 * t], h1 = shist[2 * t + 1];
    int s = h0 + h1;
    int pref = s;
#pragma unroll
    for (int off = 1; off < 64; off <<= 1) {
      int n = __shfl_up(pref, off);
      if (t >= off) pref += n;
    }
    int ex = pref - s;
    sbase[2 * t] = ex;
    scur[2 * t] = ex;
    sbase[2 * t + 1] = ex + h0;
    scur[2 * t + 1] = ex + h0;
  }
  __syncthreads();
  // place from registers (order within row arbitrary)
#pragma unroll
  for (int q = 0; q < 10; ++q) {
    int i = t + q * 512;
    if (i < cnt) {
      int rw = (int)(((unsigned)pr[q].x >> 18) & 127);
      int pos = atomicAdd(&scur[rw], 1);
      int2 o;
      o.x = pr[q].x & 0x3FFFF;
      o.y = pr[q].y;
      se[pos] = o;
    }
  }
  __syncthreads();
  // per-row gather + register accumulate (wave owns row; 2 bf16 cols/lane)
  int wave = t >> 6, lane = t & 63;
  int rbase = fb * FB_ROWS;
  for (int r = wave; r < FB_ROWS; r += 8) {
    int grow = rbase + r;
    if (grow >= N_NODES_C) break;
    int s = sbase[r];
    int n = scur[r] - s;
    float ax = 0.f, ay = 0.f;
    int tt = 0;
    for (; tt + 8 <= n; tt += 8) {
      unsigned u[8];
      float vt[8];
#pragma unroll
      for (int q = 0; q < 8; ++q) {
        int2 p = se[s + tt + q];  // uniform addr -> broadcast, conflict-free
        vt[q] = __builtin_bit_cast(float, p.y);
        u[q] = ego[(size_t)p.x * 64 + lane];
      }
#pragma unroll
      for (int q = 0; q < 8; ++q) {
        ax = fmaf(vt[q], bflo(u[q]), ax);
        ay = fmaf(vt[q], bfhi(u[q]), ay);
      }
    }
    for (; tt < n; ++tt) {
      int2 p = se[s + tt];
      float vv = __builtin_bit_cast(float, p.y);
      unsigned uu = ego[(size_t)p.x * 64 + lane];
      ax = fmaf(vv, bflo(uu), ax);
      ay = fmaf(vv, bfhi(uu), ay);
    }
    unsigned pk = (unsigned)f2bf(ax) | ((unsigned)f2bf(ay) << 16);
    side_bf[(size_t)grow * 64 + lane] = pk;
  }
}

// ---------------------------------------------------------------- fused dense layer (MFMA, split-bf16)
// Y[32][128] = Z[32][256] @ Wcat^T, Z = [side_bf16 | ego*side], ego bf16.
// side half: 2-term MFMA; prod half: 3-term.
__global__ __launch_bounds__(256) void dense_mfma(
    const unsigned short* __restrict__ side_bf, unsigned short* __restrict__ ego,
    const unsigned short* __restrict__ whi, const unsigned short* __restrict__ wlo,
    const float* __restrict__ b1, const float* __restrict__ b2,
    float* __restrict__ out) {
  __shared__ unsigned short A_hi[32 * 256];
  __shared__ unsigned short A_lo[32 * 256];  // only prod half (k>=128) used
  int t = threadIdx.x;
  int lane = t & 63;
  int w = t >> 6;
  int l15 = lane & 15;
  int lg = lane >> 4;
  int nb = blockIdx.x * 32;

#pragma unroll
  for (int i = 0; i < 4; ++i) {
    int f = i * 256 + t;
    int row = f >> 5;
    int c4 = f & 31;
    size_t g = (size_t)(nb + row) * 32 + c4;
    ushort4 sv = reinterpret_cast<const ushort4*>(side_bf)[g];
    ushort4 hv = reinterpret_cast<const ushort4*>(ego)[g];
    const unsigned short* svp = (const unsigned short*)&sv;
    const unsigned short* hvp = (const unsigned short*)&hv;
    ushort4 ph, pl;
    unsigned short* php = (unsigned short*)&ph;
    unsigned short* plp = (unsigned short*)&pl;
#pragma unroll
    for (int j = 0; j < 4; ++j) {
      float p = bf2f(svp[j]) * bf2f(hvp[j]);
      unsigned short hp2 = f2bf(p);
      php[j] = hp2;
      plp[j] = f2bf(p - bf2f(hp2));
    }
    int swz = (row & 7) << 4;
    int base_s = (row * 512 + c4 * 8) ^ swz;
    int base_p = (row * 512 + 256 + c4 * 8) ^ swz;
    *(ushort4*)((char*)A_hi + base_s) = sv;   // side bf16 (no residual)
    *(ushort4*)((char*)A_hi + base_p) = ph;
    *(ushort4*)((char*)A_lo + base_p) = pl;
  }

  float bias[2];
#pragma unroll
  for (int ntl = 0; ntl < 2; ++ntl) {
    int col = (w * 2 + ntl) * 16 + l15;
    bias[ntl] = b1[col] + b2[col];
  }

  __syncthreads();

  f32x4 zero = {0.f, 0.f, 0.f, 0.f};
  f32x4 acc[2][2] = {{zero, zero}, {zero, zero}};
#pragma unroll
  for (int kt = 0; kt < 8; ++kt) {
    int kb = kt * 64 + lg * 16;
    s16x8 a_hi[2], a_lo[2];
#pragma unroll
    for (int mt = 0; mt < 2; ++mt) {
      int row = mt * 16 + l15;
      int off = (row * 512 + kb) ^ ((row & 7) << 4);
      a_hi[mt] = *(const s16x8*)((const char*)A_hi + off);
      if (kt >= 4) a_lo[mt] = *(const s16x8*)((const char*)A_lo + off);
    }
    s16x8 b_hi[2], b_lo[2];
#pragma unroll
    for (int ntl = 0; ntl < 2; ++ntl) {
      int j = (w * 2 + ntl) * 16 + l15;
      size_t woff = (size_t)j * 256 + kt * 32 + lg * 8;
      b_hi[ntl] = *(const s16x8*)(whi + woff);
      b_lo[ntl] = *(const s16x8*)(wlo + woff);
    }
#pragma unroll
    for (int mt = 0; mt < 2; ++mt)
#pragma unroll
      for (int ntl = 0; ntl < 2; ++ntl) {
        acc[mt][ntl] = MFMA16(a_hi[mt], b_hi[ntl], acc[mt][ntl]);
        acc[mt][ntl] = MFMA16(a_hi[mt], b_lo[ntl], acc[mt][ntl]);
        if (kt >= 4)
          acc[mt][ntl] = MFMA16(a_lo[mt], b_hi[ntl], acc[mt][ntl]);
      }
  }

  __syncthreads();  // done reading A; reuse as y tile

  float* ylds = (float*)A_hi;
#pragma unroll
  for (int mt = 0; mt < 2; ++mt)
#pragma unroll
    for (int ntl = 0; ntl < 2; ++ntl) {
      int col = (w * 2 + ntl) * 16 + l15;
#pragma unroll
      for (int r = 0; r < 4; ++r) {
        int row = mt * 16 + lg * 4 + r;
        float a = acc[mt][ntl][r] + bias[ntl];
        float yv = (a >= 0.f) ? a : NEG_SLOPE_C * a;
        int off = (row * 512 + col * 4) ^ ((row & 7) << 4);
        *(float*)((char*)ylds + off) = yv;
      }
    }
  __syncthreads();

#pragma unroll
  for (int i = 0; i < 4; ++i) {
    int f = i * 256 + t;
    int row = f >> 5;
    int c4 = f & 31;
    int off = (row * 512 + c4 * 16) ^ ((row & 7) << 4);
    f32x4 y = *(f32x4*)((char*)ylds + off);
    float ss = y.x * y.x + y.y * y.y + y.z * y.z + y.w * y.w;
#pragma unroll
    for (int m = 1; m <= 16; m <<= 1) ss += __shfl_xor(ss, m);
    float scale = 1.0f / fmaxf(sqrtf(ss), EPS_C);
    size_t g = (size_t)(nb + row) * 32 + c4;
    ushort4 h;
    unsigned short* hp = (unsigned short*)&h;
#pragma unroll
    for (int jj = 0; jj < 4; ++jj) hp[jj] = f2bf(y[jj]);
    reinterpret_cast<ushort4*>(ego)[g] = h;
    f32x4 o = *(const f32x4*)(out + g * 4);
    o.x += y.x * scale;
    o.y += y.y * scale;
    o.z += y.z * scale;
    o.w += y.w * scale;
    *(f32x4*)(out + g * 4) = o;
  }
}

// ---------------------------------------------------------------- launch
extern "C" void kernel_launch(void* const* d_in, const int* in_sizes, int n_in,
                              void* d_out, int out_size, void* d_ws,
                              size_t ws_size, hipStream_t stream) {
  const int* erow = (const int*)d_in[0];
  const int* ecol = (const int*)d_in[1];
  const float* eval = (const float*)d_in[2];
  const float* o_emb = (const float*)d_in[3];
  const int* u_id = (const int*)d_in[4];
  const float* user_emb = (const float*)d_in[5];
  const float* fc1_w = (const float*)d_in[6];
  const float* fc1_b = (const float*)d_in[7];
  const float* fc2_w = (const float*)d_in[8];
  const float* fc2_b = (const float*)d_in[9];
  float* out = (float*)d_out;
  int nnz = in_sizes[0];

  char* ws = (char*)d_ws;
  size_t off = 0;
  auto alloc = [&](size_t bytes) {
    void* p = ws + off;
    off += (bytes + 255) & ~(size_t)255;
    return p;
  };
  unsigned short* ego = (unsigned short*)alloc((size_t)N_NODES_C * EMBED_C * 2);
  // union region: cstage (54.1 MB, dead after refine) / side_bf (51.2 MB)
  char* unionAB = (char*)alloc((size_t)NCOARSE * CBCAP * 8);
  int2* cstage = (int2*)unionAB;
  unsigned* side_bf = (unsigned*)unionAB;
  int2* fstage = (int2*)alloc((size_t)NFINE * FCAP * 8);
  int* cgcur = (int*)alloc(NCOARSE * 4);
  int* fgcur = (int*)alloc(NFINE * 4);
  unsigned short* whi = (unsigned short*)alloc((size_t)LAYERS_C * 128 * 256 * 2);
  unsigned short* wlo = (unsigned short*)alloc((size_t)LAYERS_C * 128 * 256 * 2);

  init_gcur<<<(NFINE + 255) / 256, 256, 0, stream>>>(cgcur, fgcur);
  init_ego_out<<<(N_NODES_C * 32 + 255) / 256, 256, 0, stream>>>(
      user_emb, u_id, o_emb, ego, out);
  partition_edges<<<nnz / 2048, 256, 0, stream>>>(erow, ecol, eval, cgcur,
                                                  cstage, nnz);
  refine_buckets<<<NCOARSE * 32, 256, 0, stream>>>(cstage, cgcur, fgcur,
                                                   fstage);
  prep_w<<<(LAYERS_C * 128 * 256 + 255) / 256, 256, 0, stream>>>(fc1_w, fc2_w,
                                                                 whi, wlo);
  for (int l = 0; l < LAYERS_C; ++l) {
    spmm_bucket<<<NFB_USED, 512, 0, stream>>>(fstage, fgcur,
                                              (const unsigned*)ego, side_bf);
    dense_mfma<<<N_NODES_C / 32, 256, 0, stream>>>(
        (const unsigned short*)side_bf, ego, whi + (size_t)l * 32768,
        wlo + (size_t)l * 32768, fc1_b + l * EMBED_C, fc2_b + l * EMBED_C, out);
  }
}